// Round 7
// baseline (206.766 us; speedup 1.0000x reference)
//
#include <hip/hip_runtime.h>
#include <math.h>

// RBFController: B=2048, N=32 centers, D=64 dims, A=8 actions.
// One 256-thread block per batch element.
//
// R17 = R16 + epilogue overlap + x_s bank-conflict fix (bitwise outputs):
//   Critical-path model (validated by R16: cutting wave0's serial chain
//   paid ~0.7x in wall time): wave0 previously did cp-chain -> barrier ->
//   phase C (t<64 = wave0!) -> barrier -> squash (wave0!) -> barrier.
//   New: split phase T at a barrier. Part1: wave0 x-spill+Y-build,
//   waves1,2 Gram->U_s, wave3 amean(regs). barrierA. Part2 CONCURRENT:
//   wave0 backward solve + cp writes || wave3 phase C (acr in REGISTERS,
//   acr_s deleted) + squash via 5 shfls (acr[c][a],acr[a][a],acr[c][c],
//   am_a,am_c are lane-permutes of register values -- no same-wave LDS
//   RAW, R9-safe) + out0/out1/Ca_s. barrierB. out2. One barrier fewer.
//   x_s stride DD->STR(68): spill/Y-build b128s hit 8 distinct bank
//   groups (4n mod 32) instead of 16-lanes-on-4-banks. Fits exactly in
//   U2s rows 32..63 (32*68=2176). Phase C sum order, squash exprs, all
//   solves unchanged -> bitwise-identical outputs.
//
// R16: cp forward-half eliminated via phase-S x reuse (L^-1 linear over
//   the n-sum); dispatch 143->131.5.
// R14 POST-MORTEM (do not retry): fully-unrolled lane=row readlane factor
//   = 60-80KB code vs 32KB I$ -> fetch thrash; regressed.
// Binding model: per-CU DS-pipe throughput (~27K cyc/block x8 blocks/CU
//   ~= 90us floor) + wave0 serial-chain latency on top. Occupancy(R11),
//   wave-split(R12), b128(R13) all ~nil. Harness ~= dispatch + ~68us.
// Do NOT retry same-wave predicated ds_write->ds_read RAW pivot exchange
// (R9 NaN) without asm verification.

#define DD 64
#define NN 32
#define AA 8
#define NBATCH 2048
#define STR 68   // L^T / H / x_s row stride (words): 272 B, 16B-aligned rows
#define W9 9     // padded stride (kills stride-32-word bank hazards)

__device__ __forceinline__ float frl(float v, int lane) {
    return __int_as_float(__builtin_amdgcn_readlane(__float_as_int(v), lane));
}

// ---------------- prep: exp1[n][m] table + logdet_lh scalar ----------------
__global__ void rbf_prep(const float* __restrict__ centers,
                         const float* __restrict__ ls,
                         float* __restrict__ ws) {
    __shared__ float cen_s[NN * DD];
    __shared__ float il2_s[DD];
    int t = threadIdx.x;
    for (int e = t; e < NN * DD; e += 256) cen_s[e] = centers[e];
    if (t < DD) { float l = ls[t]; il2_s[t] = 1.0f / (l * l); }
    __syncthreads();
    int p = blockIdx.x * 256 + t;
    if (p < NN * NN) {
        int n = p >> 5, m = p & 31;
        float acc = 0.f;
        for (int d = 0; d < DD; ++d) {
            float df = cen_s[n * DD + d] - cen_s[m * DD + d];
            acc += df * df * il2_s[d];
        }
        ws[p] = -0.25f * acc;              // exp1[n][m]
    }
    if (blockIdx.x == 0 && t < DD) {
        float l = ls[t];
        float v = logf(0.5f * l * l);
        #pragma unroll
        for (int o = 1; o < 64; o <<= 1) v += __shfl_xor(v, o, 64);
        if (t == 0) ws[NN * NN] = v;       // logdet_lh
    }
}

// Wave-local panel factorization (PROVEN shfl version). PRECONDITION:
// executing wave owns cols 16p..16p+15 of A (lane lw: rows 4*(lw&15)..,
// panel-local col tile lw>>4).
__device__ __forceinline__ void factor_panel(float (&A)[4][4], const int p,
    float* __restrict__ LmT, float* __restrict__ diag_s, float* __restrict__ invd_s,
    const int lw)
{
    const int rb  = lw & 15;
    const int cbl = lw >> 4;
    const int c0  = 16 * p + 4 * cbl;
    const int r0  = 4 * rb;
    #pragma unroll
    for (int jj = 0; jj < 16; ++jj) {
        const int q  = jj >> 2;
        const int ci = jj & 3;
        const int j  = 16 * p + jj;
        const int fsrc = rb | (q << 4);
        const int hsrc = (4 * p + cbl) | (q << 4);
        const int dsrc = (4 * p + q) | (q << 4);   // compile-time constant
        float d  = frl(A[ci][ci], dsrc);           // VALU readlane, not DS
        float f0 = __shfl(A[0][ci], fsrc, 64);
        float f1 = __shfl(A[1][ci], fsrc, 64);
        float f2 = __shfl(A[2][ci], fsrc, 64);
        float f3 = __shfl(A[3][ci], fsrc, 64);
        float h0 = __shfl(A[0][ci], hsrc, 64);
        float h1 = __shfl(A[1][ci], hsrc, 64);
        float h2 = __shfl(A[2][ci], hsrc, 64);
        float h3 = __shfl(A[3][ci], hsrc, 64);
        float id = __builtin_amdgcn_rcpf(d);   // cond(A) ~ 1; ~1ulp fine
        float fr[4];
        fr[0] = (r0 + 0 > j) ? f0 : 0.f;
        fr[1] = (r0 + 1 > j) ? f1 : 0.f;
        fr[2] = (r0 + 2 > j) ? f2 : 0.f;
        fr[3] = (r0 + 3 > j) ? f3 : 0.f;
        float hc[4];
        hc[0] = (c0 + 0 > j) ? h0 * id : 0.f;
        hc[1] = (c0 + 1 > j) ? h1 * id : 0.f;
        hc[2] = (c0 + 2 > j) ? h2 * id : 0.f;
        hc[3] = (c0 + 3 > j) ? h3 * id : 0.f;
        #pragma unroll
        for (int s = 0; s < 4; ++s)
            #pragma unroll
            for (int c = 0; c < 4; ++c)
                A[s][c] -= fr[s] * hc[c];
        if (cbl == 0) {
            float4 v = make_float4(fr[0] * id, fr[1] * id, fr[2] * id, fr[3] * id);
            *(float4*)&LmT[j * STR + r0] = v;
        }
        if (lw == jj) { diag_s[j] = d; invd_s[j] = id; }
    }
}

// Rank-16 trailing update, single matrix. Zero-filled L^T rows auto-mask <=k.
__device__ __forceinline__ void trailing_one(float (&A)[4][4], const int p,
    const float* __restrict__ LmT, const float* __restrict__ diag_s,
    const int rb, const int cbX)
{
    #pragma unroll 2
    for (int kk = 0; kk < 16; ++kk) {
        const int k = 16 * p + kk;
        const float4 Lr = *(const float4*)&LmT[k * STR + 4 * rb];
        const float4 Lc = *(const float4*)&LmT[k * STR + 4 * cbX];
        const float dk = diag_s[k];
        const float h0 = Lc.x * dk, h1 = Lc.y * dk, h2 = Lc.z * dk, h3 = Lc.w * dk;
        A[0][0] -= Lr.x * h0; A[0][1] -= Lr.x * h1; A[0][2] -= Lr.x * h2; A[0][3] -= Lr.x * h3;
        A[1][0] -= Lr.y * h0; A[1][1] -= Lr.y * h1; A[1][2] -= Lr.y * h2; A[1][3] -= Lr.y * h3;
        A[2][0] -= Lr.z * h0; A[2][1] -= Lr.z * h1; A[2][2] -= Lr.z * h2; A[2][3] -= Lr.z * h3;
        A[3][0] -= Lr.w * h0; A[3][1] -= Lr.w * h1; A[3][2] -= Lr.w * h2; A[3][3] -= Lr.w * h3;
    }
}

__global__ __launch_bounds__(256, 3) void rbf_main(
    const float* __restrict__ mean,      // (B,64)
    const float* __restrict__ cov,       // (B,64,64)
    const float* __restrict__ centers,   // (32,64)
    const float* __restrict__ weights,   // (32,8)
    const float* __restrict__ ls,        // (64,)
    const float* __restrict__ ws,        // exp1[1024], logdet_lh at [1024]
    float* __restrict__ out)
{
    __shared__ __align__(16) float LmT1[DD * STR];  // 17408 B  L1^T (M1)
    __shared__ __align__(16) float U2s[DD * STR];   // 17408 B  UNION (see header)
    __shared__ __align__(16) float phiwc[NN * AA];  // 1024 B compact (b128 reads)
    __shared__ float diag1[DD], invd1[DD], diag2[DD], invd2[DD];
    __shared__ float mean_s[DD], invl_s[DD], l2h_s[DD];
    __shared__ float w9_s[NN * W9], U_s[NN * W9];
    __shared__ float Ca_s[AA];
    __shared__ float ldlh_s;
    // total ~40.1 KB -> 4 blocks/CU

    // Union views.
    //   LmT2: factorization .. end of phase S (waves 0/1 read rows 0..63).
    //   H_s rows 0..31: overlay, written by wave1 AFTER its last LmT2 read
    //     (same-wave data dependence, R11-proven).
    //   x_s rows 32..63 (32 x STR = 2176 words, exact fit): wave0's
    //     forward-solved x, written AFTER the phase-S barrier (LmT2 dead).
    //     Stride STR -> 4n mod 32 bank rotation, conflict-free b128s.
    //   cp_s: overlays x_s base after Y-build consumed x (same-wave order).
    float* const LmT2 = U2s;
    float* const H_s  = U2s;                       // 32 rows x STR
    float* const x_s  = U2s + NN * STR;            // 32 rows x STR
    float* const cp_s = U2s + NN * STR;            // 576 words, after x dead

    const int t   = threadIdx.x;
    const int b   = blockIdx.x;
    const int lw  = t & 63;
    const int wv  = t >> 6;
    const int rb  = t & 15;            // row tile (rows 4rb..4rb+3), both matrices
    const int cb  = t >> 4;            // M2 col tile; wave w owns M2 cols 16w..16w+15
    const int cb1 = (cb + 8) & 15;     // M1 col tile; wave w owns M1 panel (w+2)&3
    const int wp1 = (wv + 2) & 3;      // M1 panel owned by this wave
    const int l8  = t & 7;             // lane-in-group (rows 8*l8..8*l8+7)
    const float* cvb = cov + (size_t)b * DD * DD;

    // ---- stage small arrays ----
    if (t < DD) {
        float l = ls[t];
        invl_s[t] = 1.0f / l;
        l2h_s[t]  = 0.5f * l * l;
        mean_s[t] = mean[(size_t)b * DD + t];
    }
    w9_s[(t >> 3) * W9 + (t & 7)] = weights[t];
    if (t == 0) ldlh_s = ws[NN * NN];
    __syncthreads();

    // ---- build tiles: A2 at (4rb, 4cb), A1 at (4rb, 4cb1) — symmetric loads
    float A1[4][4], A2[4][4];
    {
        #pragma unroll
        for (int c = 0; c < 4; ++c) {
            const int gr = 4 * cb + c;
            const float4 cv = *(const float4*)(cvb + (size_t)gr * DD + 4 * rb);
            A2[0][c] = cv.x + ((4*rb+0 == gr) ? l2h_s[gr] : 0.0f);
            A2[1][c] = cv.y + ((4*rb+1 == gr) ? l2h_s[gr] : 0.0f);
            A2[2][c] = cv.z + ((4*rb+2 == gr) ? l2h_s[gr] : 0.0f);
            A2[3][c] = cv.w + ((4*rb+3 == gr) ? l2h_s[gr] : 0.0f);
        }
        const float il0 = invl_s[4*rb+0], il1 = invl_s[4*rb+1],
                    il2 = invl_s[4*rb+2], il3 = invl_s[4*rb+3];
        #pragma unroll
        for (int c = 0; c < 4; ++c) {
            const int gr = 4 * cb1 + c;
            const float4 cv = *(const float4*)(cvb + (size_t)gr * DD + 4 * rb);
            const float ilc = invl_s[gr];
            A1[0][c] = cv.x * il0 * ilc + ((4*rb+0 == gr) ? 1.0f : 0.0f);
            A1[1][c] = cv.y * il1 * ilc + ((4*rb+1 == gr) ? 1.0f : 0.0f);
            A1[2][c] = cv.z * il2 * ilc + ((4*rb+2 == gr) ? 1.0f : 0.0f);
            A1[3][c] = cv.w * il3 * ilc + ((4*rb+3 == gr) ? 1.0f : 0.0f);
        }
    }

    // ---- FUSED factorization with wave-uniform trailing skip ----
    if (wv == 0) factor_panel(A2, 0, LmT2, diag2, invd2, lw);
    if (wv == 2) factor_panel(A1, 0, LmT1, diag1, invd1, lw);
    #pragma unroll 1
    for (int p = 0; p < 3; ++p) {
        __syncthreads();
        if (wv  >= p + 1) trailing_one(A2, p, LmT2, diag2, rb, cb);
        if (wp1 >= p + 1) trailing_one(A1, p, LmT1, diag1, rb, cb1);
        if (wv == p + 1)         factor_panel(A2, p + 1, LmT2, diag2, invd2, lw);
        if (wv == ((p + 3) & 3)) factor_panel(A1, p + 1, LmT1, diag1, invd1, lw);
    }
    __syncthreads();

    // ---- per-wave logdets (redundant; no barrier needed) ----
    float logdet1, cq;
    {
        float v1 = logf(diag1[lw]);
        float v2 = logf(diag2[lw]);
        #pragma unroll
        for (int o = 1; o < 64; o <<= 1) {
            v1 += __shfl_xor(v1, o, 64);
            v2 += __shfl_xor(v2, o, 64);
        }
        logdet1 = v1;
        cq = expf(0.5f * (ldlh_s - v2));
    }

    // ---- phase S: wave0 = M1 solve (32 RHS, 4/lane); wave1 = M2 solve ----
    // Wave0's x kept in registers across the barrier for phase-T reuse.
    const int gr8 = lw >> 3;           // RHS n = gr8 + 8*rr (waves 0,1)
    float xs0[8], xs1[8], xs2[8], xs3[8];
    if (wv == 0) {
        #pragma unroll
        for (int rr = 0; rr < 4; ++rr) {
            const int n = gr8 + 8 * rr;
            const float4 ca = *(const float4*)(centers + n * DD + 8 * l8);
            const float4 cz = *(const float4*)(centers + n * DD + 8 * l8 + 4);
            float da[8] = {ca.x,ca.y,ca.z,ca.w,cz.x,cz.y,cz.z,cz.w};
            float* xp = (rr == 0) ? xs0 : (rr == 1) ? xs1 : (rr == 2) ? xs2 : xs3;
            #pragma unroll
            for (int s = 0; s < 8; ++s) {
                const int i = 8 * l8 + s;
                xp[s] = (da[s] - mean_s[i]) * invl_s[i];
            }
        }
        for (int k8 = 0; k8 < 8; ++k8) {
            #pragma unroll
            for (int kk = 0; kk < 8; ++kk) {
                const int k = 8 * k8 + kk;
                const int src = (lw & 56) | k8;
                float z0 = __shfl(xs0[kk], src, 64);
                float z1 = __shfl(xs1[kk], src, 64);
                float z2 = __shfl(xs2[kk], src, 64);
                float z3 = __shfl(xs3[kk], src, 64);
                const float4 LA = *(const float4*)&LmT1[k * STR + 8 * l8];
                const float4 LB = *(const float4*)&LmT1[k * STR + 8 * l8 + 4];
                float l1[8] = {LA.x,LA.y,LA.z,LA.w,LB.x,LB.y,LB.z,LB.w};
                #pragma unroll
                for (int s = 0; s < 8; ++s) {
                    xs0[s] -= l1[s] * z0;
                    xs1[s] -= l1[s] * z1;
                    xs2[s] -= l1[s] * z2;
                    xs3[s] -= l1[s] * z3;
                }
            }
        }
        #pragma unroll
        for (int rr = 0; rr < 4; ++rr) {
            const int n = gr8 + 8 * rr;
            const float* xp = (rr == 0) ? xs0 : (rr == 1) ? xs1 : (rr == 2) ? xs2 : xs3;
            float qf = 0.f;
            #pragma unroll
            for (int s = 0; s < 8; ++s) qf += xp[s] * xp[s] * invd1[8 * l8 + s];
            qf += __shfl_xor(qf, 1, 64);
            qf += __shfl_xor(qf, 2, 64);
            qf += __shfl_xor(qf, 4, 64);
            float ph = expf(-0.5f * (logdet1 + qf));
            phiwc[n * AA + l8] = ph * w9_s[n * W9 + l8];
        }
    } else if (wv == 1) {
        float x0[8], x1v[8], x2v[8], x3v[8];
        #pragma unroll
        for (int rr = 0; rr < 4; ++rr) {
            const int n = gr8 + 8 * rr;
            const float4 ca = *(const float4*)(centers + n * DD + 8 * l8);
            const float4 cz = *(const float4*)(centers + n * DD + 8 * l8 + 4);
            float da[8] = {ca.x,ca.y,ca.z,ca.w,cz.x,cz.y,cz.z,cz.w};
            float* xp = (rr == 0) ? x0 : (rr == 1) ? x1v : (rr == 2) ? x2v : x3v;
            #pragma unroll
            for (int s = 0; s < 8; ++s) {
                const int i = 8 * l8 + s;
                xp[s] = 0.5f * (da[s] - mean_s[i]);
            }
        }
        for (int k8 = 0; k8 < 8; ++k8) {
            #pragma unroll
            for (int kk = 0; kk < 8; ++kk) {
                const int k = 8 * k8 + kk;
                const int src = (lw & 56) | k8;
                float z0 = __shfl(x0[kk],  src, 64);
                float z1 = __shfl(x1v[kk], src, 64);
                float z2 = __shfl(x2v[kk], src, 64);
                float z3 = __shfl(x3v[kk], src, 64);
                const float4 MA = *(const float4*)&LmT2[k * STR + 8 * l8];
                const float4 MB = *(const float4*)&LmT2[k * STR + 8 * l8 + 4];
                float l2[8] = {MA.x,MA.y,MA.z,MA.w,MB.x,MB.y,MB.z,MB.w};
                #pragma unroll
                for (int s = 0; s < 8; ++s) {
                    x0[s]  -= l2[s] * z0;
                    x1v[s] -= l2[s] * z1;
                    x2v[s] -= l2[s] * z2;
                    x3v[s] -= l2[s] * z3;
                }
            }
        }
        // H writes overwrite U2s rows 0..31 (= dead LmT2 rows): every value
        // written is data-dependent on ALL LmT2 reads above -> ordered.
        #pragma unroll
        for (int rr = 0; rr < 4; ++rr) {
            const int n = gr8 + 8 * rr;
            const float* xp = (rr == 0) ? x0 : (rr == 1) ? x1v : (rr == 2) ? x2v : x3v;
            float h[8];
            #pragma unroll
            for (int s = 0; s < 8; ++s) h[s] = xp[s] * sqrtf(invd2[8 * l8 + s]);
            *(float4*)&H_s[n * STR + 8 * l8]     = make_float4(h[0],h[1],h[2],h[3]);
            *(float4*)&H_s[n * STR + 8 * l8 + 4] = make_float4(h[4],h[5],h[6],h[7]);
        }
    }
    __syncthreads();

    // ---- phase T part 1: wave0 x-spill + Y-build | waves1,2 Gram | wave3 amean
    const int aa = lw >> 3;            // RHS col for wave0's cp path
    float y[8];
    float amv = 0.f;                   // wave3, lanes<8: am[lw]
    if (wv == 0) {
        // Spill x to x_s (U2s rows 32+; LmT2 dead after the barrier above).
        #pragma unroll
        for (int rr = 0; rr < 4; ++rr) {
            const int n = gr8 + 8 * rr;
            const float* xp = (rr == 0) ? xs0 : (rr == 1) ? xs1 : (rr == 2) ? xs2 : xs3;
            *(float4*)&x_s[n * STR + 8 * l8]     = make_float4(xp[0],xp[1],xp[2],xp[3]);
            *(float4*)&x_s[n * STR + 8 * l8 + 4] = make_float4(xp[4],xp[5],xp[6],xp[7]);
        }
        // Y-build: y[s] = sum_n x_n[8*l8+s] * phiw[n][aa] (== L^-1 K).
        #pragma unroll
        for (int s = 0; s < 8; ++s) y[s] = 0.f;
        for (int n = 0; n < NN; ++n) {
            const float pw = phiwc[n * AA + aa];
            const float4 xa = *(const float4*)&x_s[n * STR + 8 * l8];
            const float4 xb = *(const float4*)&x_s[n * STR + 8 * l8 + 4];
            y[0] += xa.x * pw; y[1] += xa.y * pw;
            y[2] += xa.z * pw; y[3] += xa.w * pw;
            y[4] += xb.x * pw; y[5] += xb.y * pw;
            y[6] += xb.z * pw; y[7] += xb.w * pw;
        }
    } else if (wv == 3) {
        if (lw < AA) {
            for (int n = 0; n < NN; ++n) amv += phiwc[n * AA + lw];
        }
    } else {
        // Gram pairs: 16 groups (waves 1,2) x 2 rows (n0=g, n1=g+16)
        const int g16 = (lw >> 3) + 8 * (wv - 1);
        const int n0 = g16, n1 = g16 + 16;
        float acc0[4] = {0.f,0.f,0.f,0.f}, acc1[4] = {0.f,0.f,0.f,0.f};
        const int rot = 2 * l8;
        #pragma unroll 2
        for (int e = 0; e < 16; ++e) {
            const int e4 = 4 * ((e + rot) & 15);
            const float4 hn0 = *(const float4*)&H_s[n0 * STR + e4];
            const float4 hn1 = *(const float4*)&H_s[n1 * STR + e4];
            #pragma unroll
            for (int mm = 0; mm < 4; ++mm) {
                const float4 hm = *(const float4*)&H_s[(4 * l8 + mm) * STR + e4];
                {
                    float s0 = hn0.x + hm.x, s1 = hn0.y + hm.y;
                    float s2 = hn0.z + hm.z, s3 = hn0.w + hm.w;
                    acc0[mm] += s0*s0 + s1*s1 + s2*s2 + s3*s3;
                }
                {
                    float s0 = hn1.x + hm.x, s1 = hn1.y + hm.y;
                    float s2 = hn1.z + hm.z, s3 = hn1.w + hm.w;
                    acc1[mm] += s0*s0 + s1*s1 + s2*s2 + s3*s3;
                }
            }
        }
        const float4 e1a = *(const float4*)&ws[n0 * NN + 4 * l8];
        const float4 e1b = *(const float4*)&ws[n1 * NN + 4 * l8];
        float Q0a = cq * expf(e1a.x - 0.5f * acc0[0]);
        float Q1a = cq * expf(e1a.y - 0.5f * acc0[1]);
        float Q2a = cq * expf(e1a.z - 0.5f * acc0[2]);
        float Q3a = cq * expf(e1a.w - 0.5f * acc0[3]);
        float Q0b = cq * expf(e1b.x - 0.5f * acc1[0]);
        float Q1b = cq * expf(e1b.y - 0.5f * acc1[1]);
        float Q2b = cq * expf(e1b.z - 0.5f * acc1[2]);
        float Q3b = cq * expf(e1b.w - 0.5f * acc1[3]);
        float ua[8], ub[8];
        #pragma unroll
        for (int a = 0; a < 8; ++a) {
            const float w0 = w9_s[(4*l8+0)*W9 + a], w1 = w9_s[(4*l8+1)*W9 + a];
            const float w2 = w9_s[(4*l8+2)*W9 + a], w3 = w9_s[(4*l8+3)*W9 + a];
            ua[a] = Q0a*w0 + Q1a*w1 + Q2a*w2 + Q3a*w3;
            ub[a] = Q0b*w0 + Q1b*w1 + Q2b*w2 + Q3b*w3;
            ua[a] += __shfl_xor(ua[a], 1, 64);
            ua[a] += __shfl_xor(ua[a], 2, 64);
            ua[a] += __shfl_xor(ua[a], 4, 64);
            ub[a] += __shfl_xor(ub[a], 1, 64);
            ub[a] += __shfl_xor(ub[a], 2, 64);
            ub[a] += __shfl_xor(ub[a], 4, 64);
        }
        float uva = (l8 == 0) ? ua[0] : (l8 == 1) ? ua[1] : (l8 == 2) ? ua[2] : (l8 == 3) ? ua[3]
                  : (l8 == 4) ? ua[4] : (l8 == 5) ? ua[5] : (l8 == 6) ? ua[6] : ua[7];
        float uvb = (l8 == 0) ? ub[0] : (l8 == 1) ? ub[1] : (l8 == 2) ? ub[2] : (l8 == 3) ? ub[3]
                  : (l8 == 4) ? ub[4] : (l8 == 5) ? ub[5] : (l8 == 6) ? ub[6] : ub[7];
        U_s[n0 * W9 + l8] = uva;
        U_s[n1 * W9 + l8] = uvb;
    }
    __syncthreads();   // barrierA: U_s published; x consumed

    // ---- phase T part 2 (CONCURRENT): wave0 backward+cp || wave3 C+squash
    float* out0 = out;
    float* out1 = out + (size_t)NBATCH * AA;
    float* out2 = out + (size_t)NBATCH * AA + (size_t)NBATCH * AA * AA;
    if (wv == 0) {
        #pragma unroll
        for (int s = 0; s < 8; ++s) y[s] *= invd1[8 * l8 + s];
        for (int i8 = 7; i8 >= 0; --i8) {             // backward (L^T), dot-form
            #pragma unroll
            for (int ii = 7; ii >= 0; --ii) {
                const int i = 8 * i8 + ii;
                const float4 r0 = *(const float4*)&LmT1[i * STR + 8 * l8];
                const float4 r1 = *(const float4*)&LmT1[i * STR + 8 * l8 + 4];
                float part = r0.x*y[0] + r0.y*y[1] + r0.z*y[2] + r0.w*y[3]
                           + r1.x*y[4] + r1.y*y[5] + r1.z*y[6] + r1.w*y[7];
                part += __shfl_xor(part, 1, 64);
                part += __shfl_xor(part, 2, 64);
                part += __shfl_xor(part, 4, 64);
                if (l8 == i8) y[ii] -= part;
            }
        }
        // cp_s overlays x_s base: x fully consumed by Y-build (same wave +
        // barrierA since).
        #pragma unroll
        for (int s = 0; s < 8; ++s)
            cp_s[(8 * l8 + s) * W9 + aa] = y[s] * invl_s[8 * l8 + s];
    } else if (wv == 3) {
        // Phase C in registers: lane (a=lw>>3, c=lw&7) owns acr[a][c].
        const int a = lw >> 3, c = lw & 7;
        float acr_ac = 0.f;
        for (int n = 0; n < NN; ++n)
            acr_ac += w9_s[n * W9 + a] * U_s[n * W9 + c];
        // Cross entries via lane permutes (register-only, R9-safe).
        const float acr_ca = __shfl(acr_ac, 8 * c + a, 64);
        const float acr_aa = __shfl(acr_ac, 9 * a, 64);
        const float acr_cc = __shfl(acr_ac, 9 * c, 64);
        const float am_a   = __shfl(amv, a, 64);
        const float am_c   = __shfl(amv, c, 64);
        const float vac = 0.5f * (acr_ac + acr_ca)
                        - am_a * am_c + ((a == c) ? 1e-6f : 0.0f);
        const float dca = acr_aa - am_a * am_a + 1e-6f;
        const float dcc = acr_cc - am_c * am_c + 1e-6f;
        const float q = expf(-0.5f * (dca + dcc));
        // expm1 formulation avoids catastrophic cancellation at vac ~ 1e-6
        const float sq = 0.5f * q * (expm1f(vac) * cosf(am_a - am_c)
                                   - expm1f(-vac) * cosf(am_a + am_c));
        out1[(size_t)b * 64 + lw] = sq;
        if (lw < AA) {
            // a==0, c==lw here: dcc == acr[lw][lw] - am[lw]^2 + 1e-6 == dct
            float e = expf(-0.5f * dcc);
            out0[(size_t)b * AA + lw] = e * sinf(am_c);
            Ca_s[lw] = e * cosf(am_c);
        }
    }
    __syncthreads();   // barrierB: cp_s + Ca_s published

    #pragma unroll
    for (int e = 0; e < 2; ++e) {
        int idx = t + 256 * e;
        out2[(size_t)b * 512 + idx] = cp_s[(idx >> 3) * W9 + (idx & 7)] * Ca_s[idx & 7];
    }
}

extern "C" void kernel_launch(void* const* d_in, const int* in_sizes, int n_in,
                              void* d_out, int out_size, void* d_ws, size_t ws_size,
                              hipStream_t stream) {
    (void)in_sizes; (void)n_in; (void)out_size; (void)ws_size;
    const float* mean    = (const float*)d_in[0];
    const float* cov     = (const float*)d_in[1];
    const float* centers = (const float*)d_in[2];
    const float* weights = (const float*)d_in[3];
    const float* ls      = (const float*)d_in[4];
    float* ws = (float*)d_ws;
    float* o  = (float*)d_out;
    rbf_prep<<<4, 256, 0, stream>>>(centers, ls, ws);
    rbf_main<<<NBATCH, 256, 0, stream>>>(mean, cov, centers, weights, ls, ws, o);
}

// Round 8
// 199.452 us; speedup vs baseline: 1.0367x; 1.0367x over previous
//
#include <hip/hip_runtime.h>
#include <math.h>

// RBFController: B=2048, N=32 centers, D=64 dims, A=8 actions.
// One 256-thread block per batch element.
//
// R18 = R16 EXACT phase structure (proven best: 131.5us dispatch, 201.9
// harness, bitwise absmax) + x_s stride STR (R17's only neutral piece).
//
// R17 POST-MORTEM (do not retry): splitting phase T at a barrier to
// overlap {backward solve || phase C} FORCED wave0 to wait for Gram
// before its backward solve: total = max(Ybuild,Gram)+backward+tail
// vs R16's max(fullchain,Gram)+tail. Gram ~= fullchain, so it
// serialized ~4K cyc to hide ~1.5K. Overlap edits must compare max()
// compositions of wave timelines, not just "what got hidden".
// R16 WIN (+9%): cp forward-half eliminated via phase-S x reuse
//   (L^-1 linear over the n-sum); wave0 serial chain is the critical path.
// R14 POST-MORTEM (do not retry): fully-unrolled lane=row readlane factor
//   = 60-80KB code vs 32KB I$ -> fetch thrash; regressed.
// Binding model: per-CU DS-pipe throughput (~27K cyc/block x8 blocks/CU
//   ~= 90us floor) + wave0 serial-chain latency. Occupancy(R11),
//   wave-split(R12), b128(R13), epilogue-overlap(R17) all nil/regress.
//   Harness ~= dispatch + ~68us fixed overhead.
// Do NOT retry same-wave predicated ds_write->ds_read RAW pivot exchange
// (R9 NaN) without asm verification.

#define DD 64
#define NN 32
#define AA 8
#define NBATCH 2048
#define STR 68   // L^T / H / x_s row stride (words): 272 B, 16B-aligned rows
#define W9 9     // padded stride (kills stride-32-word bank hazards)

__device__ __forceinline__ float frl(float v, int lane) {
    return __int_as_float(__builtin_amdgcn_readlane(__float_as_int(v), lane));
}

// ---------------- prep: exp1[n][m] table + logdet_lh scalar ----------------
__global__ void rbf_prep(const float* __restrict__ centers,
                         const float* __restrict__ ls,
                         float* __restrict__ ws) {
    __shared__ float cen_s[NN * DD];
    __shared__ float il2_s[DD];
    int t = threadIdx.x;
    for (int e = t; e < NN * DD; e += 256) cen_s[e] = centers[e];
    if (t < DD) { float l = ls[t]; il2_s[t] = 1.0f / (l * l); }
    __syncthreads();
    int p = blockIdx.x * 256 + t;
    if (p < NN * NN) {
        int n = p >> 5, m = p & 31;
        float acc = 0.f;
        for (int d = 0; d < DD; ++d) {
            float df = cen_s[n * DD + d] - cen_s[m * DD + d];
            acc += df * df * il2_s[d];
        }
        ws[p] = -0.25f * acc;              // exp1[n][m]
    }
    if (blockIdx.x == 0 && t < DD) {
        float l = ls[t];
        float v = logf(0.5f * l * l);
        #pragma unroll
        for (int o = 1; o < 64; o <<= 1) v += __shfl_xor(v, o, 64);
        if (t == 0) ws[NN * NN] = v;       // logdet_lh
    }
}

// Wave-local panel factorization (PROVEN shfl version). PRECONDITION:
// executing wave owns cols 16p..16p+15 of A (lane lw: rows 4*(lw&15)..,
// panel-local col tile lw>>4).
__device__ __forceinline__ void factor_panel(float (&A)[4][4], const int p,
    float* __restrict__ LmT, float* __restrict__ diag_s, float* __restrict__ invd_s,
    const int lw)
{
    const int rb  = lw & 15;
    const int cbl = lw >> 4;
    const int c0  = 16 * p + 4 * cbl;
    const int r0  = 4 * rb;
    #pragma unroll
    for (int jj = 0; jj < 16; ++jj) {
        const int q  = jj >> 2;
        const int ci = jj & 3;
        const int j  = 16 * p + jj;
        const int fsrc = rb | (q << 4);
        const int hsrc = (4 * p + cbl) | (q << 4);
        const int dsrc = (4 * p + q) | (q << 4);   // compile-time constant
        float d  = frl(A[ci][ci], dsrc);           // VALU readlane, not DS
        float f0 = __shfl(A[0][ci], fsrc, 64);
        float f1 = __shfl(A[1][ci], fsrc, 64);
        float f2 = __shfl(A[2][ci], fsrc, 64);
        float f3 = __shfl(A[3][ci], fsrc, 64);
        float h0 = __shfl(A[0][ci], hsrc, 64);
        float h1 = __shfl(A[1][ci], hsrc, 64);
        float h2 = __shfl(A[2][ci], hsrc, 64);
        float h3 = __shfl(A[3][ci], hsrc, 64);
        float id = __builtin_amdgcn_rcpf(d);   // cond(A) ~ 1; ~1ulp fine
        float fr[4];
        fr[0] = (r0 + 0 > j) ? f0 : 0.f;
        fr[1] = (r0 + 1 > j) ? f1 : 0.f;
        fr[2] = (r0 + 2 > j) ? f2 : 0.f;
        fr[3] = (r0 + 3 > j) ? f3 : 0.f;
        float hc[4];
        hc[0] = (c0 + 0 > j) ? h0 * id : 0.f;
        hc[1] = (c0 + 1 > j) ? h1 * id : 0.f;
        hc[2] = (c0 + 2 > j) ? h2 * id : 0.f;
        hc[3] = (c0 + 3 > j) ? h3 * id : 0.f;
        #pragma unroll
        for (int s = 0; s < 4; ++s)
            #pragma unroll
            for (int c = 0; c < 4; ++c)
                A[s][c] -= fr[s] * hc[c];
        if (cbl == 0) {
            float4 v = make_float4(fr[0] * id, fr[1] * id, fr[2] * id, fr[3] * id);
            *(float4*)&LmT[j * STR + r0] = v;
        }
        if (lw == jj) { diag_s[j] = d; invd_s[j] = id; }
    }
}

// Rank-16 trailing update, single matrix. Zero-filled L^T rows auto-mask <=k.
__device__ __forceinline__ void trailing_one(float (&A)[4][4], const int p,
    const float* __restrict__ LmT, const float* __restrict__ diag_s,
    const int rb, const int cbX)
{
    #pragma unroll 2
    for (int kk = 0; kk < 16; ++kk) {
        const int k = 16 * p + kk;
        const float4 Lr = *(const float4*)&LmT[k * STR + 4 * rb];
        const float4 Lc = *(const float4*)&LmT[k * STR + 4 * cbX];
        const float dk = diag_s[k];
        const float h0 = Lc.x * dk, h1 = Lc.y * dk, h2 = Lc.z * dk, h3 = Lc.w * dk;
        A[0][0] -= Lr.x * h0; A[0][1] -= Lr.x * h1; A[0][2] -= Lr.x * h2; A[0][3] -= Lr.x * h3;
        A[1][0] -= Lr.y * h0; A[1][1] -= Lr.y * h1; A[1][2] -= Lr.y * h2; A[1][3] -= Lr.y * h3;
        A[2][0] -= Lr.z * h0; A[2][1] -= Lr.z * h1; A[2][2] -= Lr.z * h2; A[2][3] -= Lr.z * h3;
        A[3][0] -= Lr.w * h0; A[3][1] -= Lr.w * h1; A[3][2] -= Lr.w * h2; A[3][3] -= Lr.w * h3;
    }
}

__global__ __launch_bounds__(256, 3) void rbf_main(
    const float* __restrict__ mean,      // (B,64)
    const float* __restrict__ cov,       // (B,64,64)
    const float* __restrict__ centers,   // (32,64)
    const float* __restrict__ weights,   // (32,8)
    const float* __restrict__ ls,        // (64,)
    const float* __restrict__ ws,        // exp1[1024], logdet_lh at [1024]
    float* __restrict__ out)
{
    __shared__ __align__(16) float LmT1[DD * STR];  // 17408 B  L1^T (M1)
    __shared__ __align__(16) float U2s[DD * STR];   // 17408 B  UNION (see header)
    __shared__ __align__(16) float phiwc[NN * AA];  // 1024 B compact (b128 reads)
    __shared__ float diag1[DD], invd1[DD], diag2[DD], invd2[DD];
    __shared__ float mean_s[DD], invl_s[DD], l2h_s[DD];
    __shared__ float w9_s[NN * W9], U_s[NN * W9];
    __shared__ float am_s[AA], acr_s[AA * W9], Ca_s[AA];
    __shared__ float ldlh_s;
    // total ~40.3 KB -> 4 blocks/CU

    // Union views.
    //   LmT2: factorization .. end of phase S (waves 0/1 read rows 0..63).
    //   H_s rows 0..31: overlay, written by wave1 AFTER its last LmT2 read
    //     (same-wave data dependence, R11-proven).
    //   x_s rows 32..63 (32 x STR = 2176 words, exact fit): wave0's
    //     forward-solved x, written AFTER the phase-S barrier (LmT2 dead;
    //     during phase S this region is live LmT2 rows read by wave1).
    //   cp_s: overlays x_s base after Y-build consumed x (same-wave order).
    float* const LmT2 = U2s;
    float* const H_s  = U2s;                       // 32 rows x STR
    float* const x_s  = U2s + NN * STR;            // 32 rows x STR
    float* const cp_s = U2s + NN * STR;            // 576 words, after x dead

    const int t   = threadIdx.x;
    const int b   = blockIdx.x;
    const int lw  = t & 63;
    const int wv  = t >> 6;
    const int rb  = t & 15;            // row tile (rows 4rb..4rb+3), both matrices
    const int cb  = t >> 4;            // M2 col tile; wave w owns M2 cols 16w..16w+15
    const int cb1 = (cb + 8) & 15;     // M1 col tile; wave w owns M1 panel (w+2)&3
    const int wp1 = (wv + 2) & 3;      // M1 panel owned by this wave
    const int l8  = t & 7;             // lane-in-group (rows 8*l8..8*l8+7)
    const float* cvb = cov + (size_t)b * DD * DD;

    // ---- stage small arrays ----
    if (t < DD) {
        float l = ls[t];
        invl_s[t] = 1.0f / l;
        l2h_s[t]  = 0.5f * l * l;
        mean_s[t] = mean[(size_t)b * DD + t];
    }
    w9_s[(t >> 3) * W9 + (t & 7)] = weights[t];
    if (t == 0) ldlh_s = ws[NN * NN];
    __syncthreads();

    // ---- build tiles: A2 at (4rb, 4cb), A1 at (4rb, 4cb1) — symmetric loads
    float A1[4][4], A2[4][4];
    {
        #pragma unroll
        for (int c = 0; c < 4; ++c) {
            const int gr = 4 * cb + c;
            const float4 cv = *(const float4*)(cvb + (size_t)gr * DD + 4 * rb);
            A2[0][c] = cv.x + ((4*rb+0 == gr) ? l2h_s[gr] : 0.0f);
            A2[1][c] = cv.y + ((4*rb+1 == gr) ? l2h_s[gr] : 0.0f);
            A2[2][c] = cv.z + ((4*rb+2 == gr) ? l2h_s[gr] : 0.0f);
            A2[3][c] = cv.w + ((4*rb+3 == gr) ? l2h_s[gr] : 0.0f);
        }
        const float il0 = invl_s[4*rb+0], il1 = invl_s[4*rb+1],
                    il2 = invl_s[4*rb+2], il3 = invl_s[4*rb+3];
        #pragma unroll
        for (int c = 0; c < 4; ++c) {
            const int gr = 4 * cb1 + c;
            const float4 cv = *(const float4*)(cvb + (size_t)gr * DD + 4 * rb);
            const float ilc = invl_s[gr];
            A1[0][c] = cv.x * il0 * ilc + ((4*rb+0 == gr) ? 1.0f : 0.0f);
            A1[1][c] = cv.y * il1 * ilc + ((4*rb+1 == gr) ? 1.0f : 0.0f);
            A1[2][c] = cv.z * il2 * ilc + ((4*rb+2 == gr) ? 1.0f : 0.0f);
            A1[3][c] = cv.w * il3 * ilc + ((4*rb+3 == gr) ? 1.0f : 0.0f);
        }
    }

    // ---- FUSED factorization with wave-uniform trailing skip ----
    if (wv == 0) factor_panel(A2, 0, LmT2, diag2, invd2, lw);
    if (wv == 2) factor_panel(A1, 0, LmT1, diag1, invd1, lw);
    #pragma unroll 1
    for (int p = 0; p < 3; ++p) {
        __syncthreads();
        if (wv  >= p + 1) trailing_one(A2, p, LmT2, diag2, rb, cb);
        if (wp1 >= p + 1) trailing_one(A1, p, LmT1, diag1, rb, cb1);
        if (wv == p + 1)         factor_panel(A2, p + 1, LmT2, diag2, invd2, lw);
        if (wv == ((p + 3) & 3)) factor_panel(A1, p + 1, LmT1, diag1, invd1, lw);
    }
    __syncthreads();

    // ---- per-wave logdets (redundant; no barrier needed) ----
    float logdet1, cq;
    {
        float v1 = logf(diag1[lw]);
        float v2 = logf(diag2[lw]);
        #pragma unroll
        for (int o = 1; o < 64; o <<= 1) {
            v1 += __shfl_xor(v1, o, 64);
            v2 += __shfl_xor(v2, o, 64);
        }
        logdet1 = v1;
        cq = expf(0.5f * (ldlh_s - v2));
    }

    // ---- phase S: wave0 = M1 solve (32 RHS, 4/lane); wave1 = M2 solve ----
    // Wave0's x kept in registers across the barrier for phase-T reuse.
    const int gr8 = lw >> 3;           // RHS n = gr8 + 8*rr (waves 0,1)
    float xs0[8], xs1[8], xs2[8], xs3[8];
    if (wv == 0) {
        #pragma unroll
        for (int rr = 0; rr < 4; ++rr) {
            const int n = gr8 + 8 * rr;
            const float4 ca = *(const float4*)(centers + n * DD + 8 * l8);
            const float4 cz = *(const float4*)(centers + n * DD + 8 * l8 + 4);
            float da[8] = {ca.x,ca.y,ca.z,ca.w,cz.x,cz.y,cz.z,cz.w};
            float* xp = (rr == 0) ? xs0 : (rr == 1) ? xs1 : (rr == 2) ? xs2 : xs3;
            #pragma unroll
            for (int s = 0; s < 8; ++s) {
                const int i = 8 * l8 + s;
                xp[s] = (da[s] - mean_s[i]) * invl_s[i];
            }
        }
        for (int k8 = 0; k8 < 8; ++k8) {
            #pragma unroll
            for (int kk = 0; kk < 8; ++kk) {
                const int k = 8 * k8 + kk;
                const int src = (lw & 56) | k8;
                float z0 = __shfl(xs0[kk], src, 64);
                float z1 = __shfl(xs1[kk], src, 64);
                float z2 = __shfl(xs2[kk], src, 64);
                float z3 = __shfl(xs3[kk], src, 64);
                const float4 LA = *(const float4*)&LmT1[k * STR + 8 * l8];
                const float4 LB = *(const float4*)&LmT1[k * STR + 8 * l8 + 4];
                float l1[8] = {LA.x,LA.y,LA.z,LA.w,LB.x,LB.y,LB.z,LB.w};
                #pragma unroll
                for (int s = 0; s < 8; ++s) {
                    xs0[s] -= l1[s] * z0;
                    xs1[s] -= l1[s] * z1;
                    xs2[s] -= l1[s] * z2;
                    xs3[s] -= l1[s] * z3;
                }
            }
        }
        #pragma unroll
        for (int rr = 0; rr < 4; ++rr) {
            const int n = gr8 + 8 * rr;
            const float* xp = (rr == 0) ? xs0 : (rr == 1) ? xs1 : (rr == 2) ? xs2 : xs3;
            float qf = 0.f;
            #pragma unroll
            for (int s = 0; s < 8; ++s) qf += xp[s] * xp[s] * invd1[8 * l8 + s];
            qf += __shfl_xor(qf, 1, 64);
            qf += __shfl_xor(qf, 2, 64);
            qf += __shfl_xor(qf, 4, 64);
            float ph = expf(-0.5f * (logdet1 + qf));
            phiwc[n * AA + l8] = ph * w9_s[n * W9 + l8];
        }
    } else if (wv == 1) {
        float x0[8], x1v[8], x2v[8], x3v[8];
        #pragma unroll
        for (int rr = 0; rr < 4; ++rr) {
            const int n = gr8 + 8 * rr;
            const float4 ca = *(const float4*)(centers + n * DD + 8 * l8);
            const float4 cz = *(const float4*)(centers + n * DD + 8 * l8 + 4);
            float da[8] = {ca.x,ca.y,ca.z,ca.w,cz.x,cz.y,cz.z,cz.w};
            float* xp = (rr == 0) ? x0 : (rr == 1) ? x1v : (rr == 2) ? x2v : x3v;
            #pragma unroll
            for (int s = 0; s < 8; ++s) {
                const int i = 8 * l8 + s;
                xp[s] = 0.5f * (da[s] - mean_s[i]);
            }
        }
        for (int k8 = 0; k8 < 8; ++k8) {
            #pragma unroll
            for (int kk = 0; kk < 8; ++kk) {
                const int k = 8 * k8 + kk;
                const int src = (lw & 56) | k8;
                float z0 = __shfl(x0[kk],  src, 64);
                float z1 = __shfl(x1v[kk], src, 64);
                float z2 = __shfl(x2v[kk], src, 64);
                float z3 = __shfl(x3v[kk], src, 64);
                const float4 MA = *(const float4*)&LmT2[k * STR + 8 * l8];
                const float4 MB = *(const float4*)&LmT2[k * STR + 8 * l8 + 4];
                float l2[8] = {MA.x,MA.y,MA.z,MA.w,MB.x,MB.y,MB.z,MB.w};
                #pragma unroll
                for (int s = 0; s < 8; ++s) {
                    x0[s]  -= l2[s] * z0;
                    x1v[s] -= l2[s] * z1;
                    x2v[s] -= l2[s] * z2;
                    x3v[s] -= l2[s] * z3;
                }
            }
        }
        // H writes overwrite U2s rows 0..31 (= dead LmT2 rows): every value
        // written is data-dependent on ALL LmT2 reads above -> ordered.
        #pragma unroll
        for (int rr = 0; rr < 4; ++rr) {
            const int n = gr8 + 8 * rr;
            const float* xp = (rr == 0) ? x0 : (rr == 1) ? x1v : (rr == 2) ? x2v : x3v;
            float h[8];
            #pragma unroll
            for (int s = 0; s < 8; ++s) h[s] = xp[s] * sqrtf(invd2[8 * l8 + s]);
            *(float4*)&H_s[n * STR + 8 * l8]     = make_float4(h[0],h[1],h[2],h[3]);
            *(float4*)&H_s[n * STR + 8 * l8 + 4] = make_float4(h[4],h[5],h[6],h[7]);
        }
    }
    __syncthreads();

    // ---- phase T: wave0 x-spill + Y-build + backward | waves1,2 Gram | wave3 amean
    if (wv == 0) {
        // Spill x to x_s (U2s rows 32+; LmT2 dead after the barrier above).
        #pragma unroll
        for (int rr = 0; rr < 4; ++rr) {
            const int n = gr8 + 8 * rr;
            const float* xp = (rr == 0) ? xs0 : (rr == 1) ? xs1 : (rr == 2) ? xs2 : xs3;
            *(float4*)&x_s[n * STR + 8 * l8]     = make_float4(xp[0],xp[1],xp[2],xp[3]);
            *(float4*)&x_s[n * STR + 8 * l8 + 4] = make_float4(xp[4],xp[5],xp[6],xp[7]);
        }
        // Y-build: y[s] = sum_n x_n[8*l8+s] * phiw[n][aa]  (== L^-1 K by
        // linearity; forward solve eliminated). Lane layout matches the
        // backward solve below.
        const int aa = lw >> 3;
        float y[8] = {0.f,0.f,0.f,0.f,0.f,0.f,0.f,0.f};
        for (int n = 0; n < NN; ++n) {
            const float pw = phiwc[n * AA + aa];
            const float4 xa = *(const float4*)&x_s[n * STR + 8 * l8];
            const float4 xb = *(const float4*)&x_s[n * STR + 8 * l8 + 4];
            y[0] += xa.x * pw; y[1] += xa.y * pw;
            y[2] += xa.z * pw; y[3] += xa.w * pw;
            y[4] += xb.x * pw; y[5] += xb.y * pw;
            y[6] += xb.z * pw; y[7] += xb.w * pw;
        }
        #pragma unroll
        for (int s = 0; s < 8; ++s) y[s] *= invd1[8 * l8 + s];
        for (int i8 = 7; i8 >= 0; --i8) {             // backward (L^T), dot-form
            #pragma unroll
            for (int ii = 7; ii >= 0; --ii) {
                const int i = 8 * i8 + ii;
                const float4 r0 = *(const float4*)&LmT1[i * STR + 8 * l8];
                const float4 r1 = *(const float4*)&LmT1[i * STR + 8 * l8 + 4];
                float part = r0.x*y[0] + r0.y*y[1] + r0.z*y[2] + r0.w*y[3]
                           + r1.x*y[4] + r1.y*y[5] + r1.z*y[6] + r1.w*y[7];
                part += __shfl_xor(part, 1, 64);
                part += __shfl_xor(part, 2, 64);
                part += __shfl_xor(part, 4, 64);
                if (l8 == i8) y[ii] -= part;
            }
        }
        // cp_s overlays x_s base: x fully consumed by Y-build (same wave).
        #pragma unroll
        for (int s = 0; s < 8; ++s)
            cp_s[(8 * l8 + s) * W9 + aa] = y[s] * invl_s[8 * l8 + s];
    } else if (wv == 3) {
        if (lw < AA) {
            const int a = lw;
            float am = 0.f;
            for (int n = 0; n < NN; ++n) am += phiwc[n * AA + a];
            am_s[a] = am;
        }
    } else {
        // Gram pairs: 16 groups (waves 1,2) x 2 rows (n0=g, n1=g+16)
        const int g16 = (lw >> 3) + 8 * (wv - 1);
        const int n0 = g16, n1 = g16 + 16;
        float acc0[4] = {0.f,0.f,0.f,0.f}, acc1[4] = {0.f,0.f,0.f,0.f};
        const int rot = 2 * l8;
        #pragma unroll 2
        for (int e = 0; e < 16; ++e) {
            const int e4 = 4 * ((e + rot) & 15);
            const float4 hn0 = *(const float4*)&H_s[n0 * STR + e4];
            const float4 hn1 = *(const float4*)&H_s[n1 * STR + e4];
            #pragma unroll
            for (int mm = 0; mm < 4; ++mm) {
                const float4 hm = *(const float4*)&H_s[(4 * l8 + mm) * STR + e4];
                {
                    float s0 = hn0.x + hm.x, s1 = hn0.y + hm.y;
                    float s2 = hn0.z + hm.z, s3 = hn0.w + hm.w;
                    acc0[mm] += s0*s0 + s1*s1 + s2*s2 + s3*s3;
                }
                {
                    float s0 = hn1.x + hm.x, s1 = hn1.y + hm.y;
                    float s2 = hn1.z + hm.z, s3 = hn1.w + hm.w;
                    acc1[mm] += s0*s0 + s1*s1 + s2*s2 + s3*s3;
                }
            }
        }
        const float4 e1a = *(const float4*)&ws[n0 * NN + 4 * l8];
        const float4 e1b = *(const float4*)&ws[n1 * NN + 4 * l8];
        float Q0a = cq * expf(e1a.x - 0.5f * acc0[0]);
        float Q1a = cq * expf(e1a.y - 0.5f * acc0[1]);
        float Q2a = cq * expf(e1a.z - 0.5f * acc0[2]);
        float Q3a = cq * expf(e1a.w - 0.5f * acc0[3]);
        float Q0b = cq * expf(e1b.x - 0.5f * acc1[0]);
        float Q1b = cq * expf(e1b.y - 0.5f * acc1[1]);
        float Q2b = cq * expf(e1b.z - 0.5f * acc1[2]);
        float Q3b = cq * expf(e1b.w - 0.5f * acc1[3]);
        float ua[8], ub[8];
        #pragma unroll
        for (int a = 0; a < 8; ++a) {
            const float w0 = w9_s[(4*l8+0)*W9 + a], w1 = w9_s[(4*l8+1)*W9 + a];
            const float w2 = w9_s[(4*l8+2)*W9 + a], w3 = w9_s[(4*l8+3)*W9 + a];
            ua[a] = Q0a*w0 + Q1a*w1 + Q2a*w2 + Q3a*w3;
            ub[a] = Q0b*w0 + Q1b*w1 + Q2b*w2 + Q3b*w3;
            ua[a] += __shfl_xor(ua[a], 1, 64);
            ua[a] += __shfl_xor(ua[a], 2, 64);
            ua[a] += __shfl_xor(ua[a], 4, 64);
            ub[a] += __shfl_xor(ub[a], 1, 64);
            ub[a] += __shfl_xor(ub[a], 2, 64);
            ub[a] += __shfl_xor(ub[a], 4, 64);
        }
        float uva = (l8 == 0) ? ua[0] : (l8 == 1) ? ua[1] : (l8 == 2) ? ua[2] : (l8 == 3) ? ua[3]
                  : (l8 == 4) ? ua[4] : (l8 == 5) ? ua[5] : (l8 == 6) ? ua[6] : ua[7];
        float uvb = (l8 == 0) ? ub[0] : (l8 == 1) ? ub[1] : (l8 == 2) ? ub[2] : (l8 == 3) ? ub[3]
                  : (l8 == 4) ? ub[4] : (l8 == 5) ? ub[5] : (l8 == 6) ? ub[6] : ub[7];
        U_s[n0 * W9 + l8] = uva;
        U_s[n1 * W9 + l8] = uvb;
    }
    __syncthreads();

    // ---- phase C: acr = w^T U ----
    if (t < 64) {
        const int a = t >> 3, c = t & 7;
        float acc2 = 0.f;
        for (int n = 0; n < NN; ++n) acc2 += w9_s[n * W9 + a] * U_s[n * W9 + c];
        acr_s[a * W9 + c] = acc2;
    }
    __syncthreads();

    // ---- squash + outputs ----
    float* out0 = out;
    float* out1 = out + (size_t)NBATCH * AA;
    float* out2 = out + (size_t)NBATCH * AA + (size_t)NBATCH * AA * AA;
    if (t < 64) {
        const int a = t >> 3, c = t & 7;
        const float ama = am_s[a], amc = am_s[c];
        const float vac = 0.5f * (acr_s[a * W9 + c] + acr_s[c * W9 + a])
                        - ama * amc + ((a == c) ? 1e-6f : 0.0f);
        const float dca = acr_s[a * W9 + a] - ama * ama + 1e-6f;
        const float dcc = acr_s[c * W9 + c] - amc * amc + 1e-6f;
        const float q = expf(-0.5f * (dca + dcc));
        // expm1 formulation avoids catastrophic cancellation at vac ~ 1e-6
        const float sq = 0.5f * q * (expm1f(vac) * cosf(ama - amc)
                                   - expm1f(-vac) * cosf(ama + amc));
        out1[(size_t)b * 64 + t] = sq;
        if (t < AA) {
            float dct = acr_s[t * W9 + t] - am_s[t] * am_s[t] + 1e-6f;
            float e = expf(-0.5f * dct);
            out0[(size_t)b * AA + t] = e * sinf(am_s[t]);
            Ca_s[t] = e * cosf(am_s[t]);
        }
    }
    __syncthreads();
    #pragma unroll
    for (int e = 0; e < 2; ++e) {
        int idx = t + 256 * e;
        out2[(size_t)b * 512 + idx] = cp_s[(idx >> 3) * W9 + (idx & 7)] * Ca_s[idx & 7];
    }
}

extern "C" void kernel_launch(void* const* d_in, const int* in_sizes, int n_in,
                              void* d_out, int out_size, void* d_ws, size_t ws_size,
                              hipStream_t stream) {
    (void)in_sizes; (void)n_in; (void)out_size; (void)ws_size;
    const float* mean    = (const float*)d_in[0];
    const float* cov     = (const float*)d_in[1];
    const float* centers = (const float*)d_in[2];
    const float* weights = (const float*)d_in[3];
    const float* ls      = (const float*)d_in[4];
    float* ws = (float*)d_ws;
    float* o  = (float*)d_out;
    rbf_prep<<<4, 256, 0, stream>>>(centers, ls, ws);
    rbf_main<<<NBATCH, 256, 0, stream>>>(mean, cov, centers, weights, ls, ws, o);
}

// Round 9
// 199.375 us; speedup vs baseline: 1.0371x; 1.0004x over previous
//
#include <hip/hip_runtime.h>
#include <math.h>

// RBFController: B=2048, N=32 centers, D=64 dims, A=8 actions.
// One 256-thread block per batch element.
//
// R19 = R18 + blocked backward solve + LmT XOR column relayout.
//   Calibrated model (R16/R18): cycles cut from wave0's serial chain
//   convert to wall time at ~blocks/CU x1 (R16: 4K/block -> 27.6K wall).
//   Last long chain: backward solve, 64 steps x (dot + 3 DEPENDENT
//   shfl_xor) ~= 8.3K cy serial. Replaced with 8x8 block-triangular:
//   per block (descending): 8 pipelined shfls pull group-i8's final y ->
//   ALL lanes redundantly solve the 8x8 diag block lane-locally (stored
//   zeros in LmT rows mask s<=ii terms incl. unit diag) -> group i8
//   adopts -> groups l8<i8 rank-8 parallel update. Chain ~2.5K cy.
//   The update reads rows 8 apart at fixed column-group; with STR=68,
//   8 rows x 68 = 544 = 0 mod 32 -> 8-way bank conflict. Fix: XOR
//   relayout of LmT column groups: physical_off = 8*((off>>3) ^
//   ((row>>3)&7)) + (off&7). Pure address permutation (zero FP change),
//   applied at ALL LmT sites: factor write, trailing Lr/Lc, both
//   phase-S solves, backward intra (lands at group 0 -> broadcast) and
//   update (group i8^l8 -> 2-way). Fixed-row accesses keep their old
//   bank multiset (lane->group is a permutation). Only the backward
//   solve's FP ORDER changes -> absmax leaves bitwise (expect 1-4e-8;
//   prior sessions passed at 2.03e-8).
//
// R17 POST-MORTEM (do not retry): phase-T barrier split serialized
//   wave0's backward behind Gram: max() composition got worse.
// R16 WIN (+9%): cp forward-half eliminated via phase-S x reuse.
// R14 POST-MORTEM (do not retry): fully-unrolled readlane factor ->
//   I$ thrash.
// Binding model: DS-pipe throughput (~25K cyc/block x8 blocks/CU) +
//   wave0 serial-chain latency on top; occupancy/wave-split/b128 all nil.
// Do NOT retry same-wave predicated ds_write->ds_read RAW pivot exchange
// (R9 NaN) without asm verification.

#define DD 64
#define NN 32
#define AA 8
#define NBATCH 2048
#define STR 68   // L^T / H / x_s row stride (words): 272 B, 16B-aligned rows
#define W9 9     // padded stride (kills stride-32-word bank hazards)

__device__ __forceinline__ float frl(float v, int lane) {
    return __int_as_float(__builtin_amdgcn_readlane(__float_as_int(v), lane));
}

// ---------------- prep: exp1[n][m] table + logdet_lh scalar ----------------
__global__ void rbf_prep(const float* __restrict__ centers,
                         const float* __restrict__ ls,
                         float* __restrict__ ws) {
    __shared__ float cen_s[NN * DD];
    __shared__ float il2_s[DD];
    int t = threadIdx.x;
    for (int e = t; e < NN * DD; e += 256) cen_s[e] = centers[e];
    if (t < DD) { float l = ls[t]; il2_s[t] = 1.0f / (l * l); }
    __syncthreads();
    int p = blockIdx.x * 256 + t;
    if (p < NN * NN) {
        int n = p >> 5, m = p & 31;
        float acc = 0.f;
        for (int d = 0; d < DD; ++d) {
            float df = cen_s[n * DD + d] - cen_s[m * DD + d];
            acc += df * df * il2_s[d];
        }
        ws[p] = -0.25f * acc;              // exp1[n][m]
    }
    if (blockIdx.x == 0 && t < DD) {
        float l = ls[t];
        float v = logf(0.5f * l * l);
        #pragma unroll
        for (int o = 1; o < 64; o <<= 1) v += __shfl_xor(v, o, 64);
        if (t == 0) ws[NN * NN] = v;       // logdet_lh
    }
}

// Wave-local panel factorization (PROVEN shfl version) + XOR relayout on
// the L^T write. PRECONDITION: executing wave owns cols 16p..16p+15 of A.
__device__ __forceinline__ void factor_panel(float (&A)[4][4], const int p,
    float* __restrict__ LmT, float* __restrict__ diag_s, float* __restrict__ invd_s,
    const int lw)
{
    const int rb  = lw & 15;
    const int cbl = lw >> 4;
    const int c0  = 16 * p + 4 * cbl;
    const int r0  = 4 * rb;
    #pragma unroll
    for (int jj = 0; jj < 16; ++jj) {
        const int q  = jj >> 2;
        const int ci = jj & 3;
        const int j  = 16 * p + jj;
        const int fsrc = rb | (q << 4);
        const int hsrc = (4 * p + cbl) | (q << 4);
        const int dsrc = (4 * p + q) | (q << 4);   // compile-time constant
        float d  = frl(A[ci][ci], dsrc);           // VALU readlane, not DS
        float f0 = __shfl(A[0][ci], fsrc, 64);
        float f1 = __shfl(A[1][ci], fsrc, 64);
        float f2 = __shfl(A[2][ci], fsrc, 64);
        float f3 = __shfl(A[3][ci], fsrc, 64);
        float h0 = __shfl(A[0][ci], hsrc, 64);
        float h1 = __shfl(A[1][ci], hsrc, 64);
        float h2 = __shfl(A[2][ci], hsrc, 64);
        float h3 = __shfl(A[3][ci], hsrc, 64);
        float id = __builtin_amdgcn_rcpf(d);   // cond(A) ~ 1; ~1ulp fine
        float fr[4];
        fr[0] = (r0 + 0 > j) ? f0 : 0.f;
        fr[1] = (r0 + 1 > j) ? f1 : 0.f;
        fr[2] = (r0 + 2 > j) ? f2 : 0.f;
        fr[3] = (r0 + 3 > j) ? f3 : 0.f;
        float hc[4];
        hc[0] = (c0 + 0 > j) ? h0 * id : 0.f;
        hc[1] = (c0 + 1 > j) ? h1 * id : 0.f;
        hc[2] = (c0 + 2 > j) ? h2 * id : 0.f;
        hc[3] = (c0 + 3 > j) ? h3 * id : 0.f;
        #pragma unroll
        for (int s = 0; s < 4; ++s)
            #pragma unroll
            for (int c = 0; c < 4; ++c)
                A[s][c] -= fr[s] * hc[c];
        if (cbl == 0) {
            // XOR relayout: logical off 4rb -> 8*((rb>>1)^((j>>3)&7)) + 4*(rb&1)
            const int wo = 8 * ((rb >> 1) ^ ((j >> 3) & 7)) + 4 * (rb & 1);
            float4 v = make_float4(fr[0] * id, fr[1] * id, fr[2] * id, fr[3] * id);
            *(float4*)&LmT[j * STR + wo] = v;
        }
        if (lw == jj) { diag_s[j] = d; invd_s[j] = id; }
    }
}

// Rank-16 trailing update, single matrix. Zero-filled L^T rows auto-mask <=k.
// Reads follow the XOR relayout (same lane->group permutation => same bank
// multiset as the un-swizzled version).
__device__ __forceinline__ void trailing_one(float (&A)[4][4], const int p,
    const float* __restrict__ LmT, const float* __restrict__ diag_s,
    const int rb, const int cbX)
{
    #pragma unroll 2
    for (int kk = 0; kk < 16; ++kk) {
        const int k = 16 * p + kk;
        const int cs = (k >> 3) & 7;
        const float4 Lr = *(const float4*)&LmT[k * STR + 8*((rb >>1)^cs) + 4*(rb &1)];
        const float4 Lc = *(const float4*)&LmT[k * STR + 8*((cbX>>1)^cs) + 4*(cbX&1)];
        const float dk = diag_s[k];
        const float h0 = Lc.x * dk, h1 = Lc.y * dk, h2 = Lc.z * dk, h3 = Lc.w * dk;
        A[0][0] -= Lr.x * h0; A[0][1] -= Lr.x * h1; A[0][2] -= Lr.x * h2; A[0][3] -= Lr.x * h3;
        A[1][0] -= Lr.y * h0; A[1][1] -= Lr.y * h1; A[1][2] -= Lr.y * h2; A[1][3] -= Lr.y * h3;
        A[2][0] -= Lr.z * h0; A[2][1] -= Lr.z * h1; A[2][2] -= Lr.z * h2; A[2][3] -= Lr.z * h3;
        A[3][0] -= Lr.w * h0; A[3][1] -= Lr.w * h1; A[3][2] -= Lr.w * h2; A[3][3] -= Lr.w * h3;
    }
}

__global__ __launch_bounds__(256, 3) void rbf_main(
    const float* __restrict__ mean,      // (B,64)
    const float* __restrict__ cov,       // (B,64,64)
    const float* __restrict__ centers,   // (32,64)
    const float* __restrict__ weights,   // (32,8)
    const float* __restrict__ ls,        // (64,)
    const float* __restrict__ ws,        // exp1[1024], logdet_lh at [1024]
    float* __restrict__ out)
{
    __shared__ __align__(16) float LmT1[DD * STR];  // 17408 B  L1^T (M1)
    __shared__ __align__(16) float U2s[DD * STR];   // 17408 B  UNION (see header)
    __shared__ __align__(16) float phiwc[NN * AA];  // 1024 B compact (b128 reads)
    __shared__ float diag1[DD], invd1[DD], diag2[DD], invd2[DD];
    __shared__ float mean_s[DD], invl_s[DD], l2h_s[DD];
    __shared__ float w9_s[NN * W9], U_s[NN * W9];
    __shared__ float am_s[AA], acr_s[AA * W9], Ca_s[AA];
    __shared__ float ldlh_s;
    // total ~40.3 KB -> 4 blocks/CU

    // Union views (lifetimes as in R18; all overlays barrier- or same-wave
    // ordered; H_s / x_s / cp_s are LINEAR layouts, unaffected by the LmT
    // XOR relayout since their rows are fully rewritten before reads).
    float* const LmT2 = U2s;
    float* const H_s  = U2s;                       // 32 rows x STR
    float* const x_s  = U2s + NN * STR;            // 32 rows x STR
    float* const cp_s = U2s + NN * STR;            // 576 words, after x dead

    const int t   = threadIdx.x;
    const int b   = blockIdx.x;
    const int lw  = t & 63;
    const int wv  = t >> 6;
    const int rb  = t & 15;            // row tile (rows 4rb..4rb+3), both matrices
    const int cb  = t >> 4;            // M2 col tile; wave w owns M2 cols 16w..16w+15
    const int cb1 = (cb + 8) & 15;     // M1 col tile; wave w owns M1 panel (w+2)&3
    const int wp1 = (wv + 2) & 3;      // M1 panel owned by this wave
    const int l8  = t & 7;             // lane-in-group (rows 8*l8..8*l8+7)
    const float* cvb = cov + (size_t)b * DD * DD;

    // ---- stage small arrays ----
    if (t < DD) {
        float l = ls[t];
        invl_s[t] = 1.0f / l;
        l2h_s[t]  = 0.5f * l * l;
        mean_s[t] = mean[(size_t)b * DD + t];
    }
    w9_s[(t >> 3) * W9 + (t & 7)] = weights[t];
    if (t == 0) ldlh_s = ws[NN * NN];
    __syncthreads();

    // ---- build tiles: A2 at (4rb, 4cb), A1 at (4rb, 4cb1) — symmetric loads
    float A1[4][4], A2[4][4];
    {
        #pragma unroll
        for (int c = 0; c < 4; ++c) {
            const int gr = 4 * cb + c;
            const float4 cv = *(const float4*)(cvb + (size_t)gr * DD + 4 * rb);
            A2[0][c] = cv.x + ((4*rb+0 == gr) ? l2h_s[gr] : 0.0f);
            A2[1][c] = cv.y + ((4*rb+1 == gr) ? l2h_s[gr] : 0.0f);
            A2[2][c] = cv.z + ((4*rb+2 == gr) ? l2h_s[gr] : 0.0f);
            A2[3][c] = cv.w + ((4*rb+3 == gr) ? l2h_s[gr] : 0.0f);
        }
        const float il0 = invl_s[4*rb+0], il1 = invl_s[4*rb+1],
                    il2 = invl_s[4*rb+2], il3 = invl_s[4*rb+3];
        #pragma unroll
        for (int c = 0; c < 4; ++c) {
            const int gr = 4 * cb1 + c;
            const float4 cv = *(const float4*)(cvb + (size_t)gr * DD + 4 * rb);
            const float ilc = invl_s[gr];
            A1[0][c] = cv.x * il0 * ilc + ((4*rb+0 == gr) ? 1.0f : 0.0f);
            A1[1][c] = cv.y * il1 * ilc + ((4*rb+1 == gr) ? 1.0f : 0.0f);
            A1[2][c] = cv.z * il2 * ilc + ((4*rb+2 == gr) ? 1.0f : 0.0f);
            A1[3][c] = cv.w * il3 * ilc + ((4*rb+3 == gr) ? 1.0f : 0.0f);
        }
    }

    // ---- FUSED factorization with wave-uniform trailing skip ----
    if (wv == 0) factor_panel(A2, 0, LmT2, diag2, invd2, lw);
    if (wv == 2) factor_panel(A1, 0, LmT1, diag1, invd1, lw);
    #pragma unroll 1
    for (int p = 0; p < 3; ++p) {
        __syncthreads();
        if (wv  >= p + 1) trailing_one(A2, p, LmT2, diag2, rb, cb);
        if (wp1 >= p + 1) trailing_one(A1, p, LmT1, diag1, rb, cb1);
        if (wv == p + 1)         factor_panel(A2, p + 1, LmT2, diag2, invd2, lw);
        if (wv == ((p + 3) & 3)) factor_panel(A1, p + 1, LmT1, diag1, invd1, lw);
    }
    __syncthreads();

    // ---- per-wave logdets (redundant; no barrier needed) ----
    float logdet1, cq;
    {
        float v1 = logf(diag1[lw]);
        float v2 = logf(diag2[lw]);
        #pragma unroll
        for (int o = 1; o < 64; o <<= 1) {
            v1 += __shfl_xor(v1, o, 64);
            v2 += __shfl_xor(v2, o, 64);
        }
        logdet1 = v1;
        cq = expf(0.5f * (ldlh_s - v2));
    }

    // ---- phase S: wave0 = M1 solve (32 RHS, 4/lane); wave1 = M2 solve ----
    // L rows read with the XOR relayout: logical group l8 -> l8 ^ k8.
    const int gr8 = lw >> 3;           // RHS n = gr8 + 8*rr (waves 0,1)
    float xs0[8], xs1[8], xs2[8], xs3[8];
    if (wv == 0) {
        #pragma unroll
        for (int rr = 0; rr < 4; ++rr) {
            const int n = gr8 + 8 * rr;
            const float4 ca = *(const float4*)(centers + n * DD + 8 * l8);
            const float4 cz = *(const float4*)(centers + n * DD + 8 * l8 + 4);
            float da[8] = {ca.x,ca.y,ca.z,ca.w,cz.x,cz.y,cz.z,cz.w};
            float* xp = (rr == 0) ? xs0 : (rr == 1) ? xs1 : (rr == 2) ? xs2 : xs3;
            #pragma unroll
            for (int s = 0; s < 8; ++s) {
                const int i = 8 * l8 + s;
                xp[s] = (da[s] - mean_s[i]) * invl_s[i];
            }
        }
        for (int k8 = 0; k8 < 8; ++k8) {
            const int kg = 8 * (l8 ^ k8);          // SWZ(k, 8*l8), k>>3 == k8
            #pragma unroll
            for (int kk = 0; kk < 8; ++kk) {
                const int k = 8 * k8 + kk;
                const int src = (lw & 56) | k8;
                float z0 = __shfl(xs0[kk], src, 64);
                float z1 = __shfl(xs1[kk], src, 64);
                float z2 = __shfl(xs2[kk], src, 64);
                float z3 = __shfl(xs3[kk], src, 64);
                const float4 LA = *(const float4*)&LmT1[k * STR + kg];
                const float4 LB = *(const float4*)&LmT1[k * STR + kg + 4];
                float l1[8] = {LA.x,LA.y,LA.z,LA.w,LB.x,LB.y,LB.z,LB.w};
                #pragma unroll
                for (int s = 0; s < 8; ++s) {
                    xs0[s] -= l1[s] * z0;
                    xs1[s] -= l1[s] * z1;
                    xs2[s] -= l1[s] * z2;
                    xs3[s] -= l1[s] * z3;
                }
            }
        }
        #pragma unroll
        for (int rr = 0; rr < 4; ++rr) {
            const int n = gr8 + 8 * rr;
            const float* xp = (rr == 0) ? xs0 : (rr == 1) ? xs1 : (rr == 2) ? xs2 : xs3;
            float qf = 0.f;
            #pragma unroll
            for (int s = 0; s < 8; ++s) qf += xp[s] * xp[s] * invd1[8 * l8 + s];
            qf += __shfl_xor(qf, 1, 64);
            qf += __shfl_xor(qf, 2, 64);
            qf += __shfl_xor(qf, 4, 64);
            float ph = expf(-0.5f * (logdet1 + qf));
            phiwc[n * AA + l8] = ph * w9_s[n * W9 + l8];
        }
    } else if (wv == 1) {
        float x0[8], x1v[8], x2v[8], x3v[8];
        #pragma unroll
        for (int rr = 0; rr < 4; ++rr) {
            const int n = gr8 + 8 * rr;
            const float4 ca = *(const float4*)(centers + n * DD + 8 * l8);
            const float4 cz = *(const float4*)(centers + n * DD + 8 * l8 + 4);
            float da[8] = {ca.x,ca.y,ca.z,ca.w,cz.x,cz.y,cz.z,cz.w};
            float* xp = (rr == 0) ? x0 : (rr == 1) ? x1v : (rr == 2) ? x2v : x3v;
            #pragma unroll
            for (int s = 0; s < 8; ++s) {
                const int i = 8 * l8 + s;
                xp[s] = 0.5f * (da[s] - mean_s[i]);
            }
        }
        for (int k8 = 0; k8 < 8; ++k8) {
            const int kg = 8 * (l8 ^ k8);          // SWZ relayout
            #pragma unroll
            for (int kk = 0; kk < 8; ++kk) {
                const int k = 8 * k8 + kk;
                const int src = (lw & 56) | k8;
                float z0 = __shfl(x0[kk],  src, 64);
                float z1 = __shfl(x1v[kk], src, 64);
                float z2 = __shfl(x2v[kk], src, 64);
                float z3 = __shfl(x3v[kk], src, 64);
                const float4 MA = *(const float4*)&LmT2[k * STR + kg];
                const float4 MB = *(const float4*)&LmT2[k * STR + kg + 4];
                float l2[8] = {MA.x,MA.y,MA.z,MA.w,MB.x,MB.y,MB.z,MB.w};
                #pragma unroll
                for (int s = 0; s < 8; ++s) {
                    x0[s]  -= l2[s] * z0;
                    x1v[s] -= l2[s] * z1;
                    x2v[s] -= l2[s] * z2;
                    x3v[s] -= l2[s] * z3;
                }
            }
        }
        // H writes overwrite U2s rows 0..31 (= dead LmT2 rows): every value
        // written is data-dependent on ALL LmT2 reads above -> ordered.
        #pragma unroll
        for (int rr = 0; rr < 4; ++rr) {
            const int n = gr8 + 8 * rr;
            const float* xp = (rr == 0) ? x0 : (rr == 1) ? x1v : (rr == 2) ? x2v : x3v;
            float h[8];
            #pragma unroll
            for (int s = 0; s < 8; ++s) h[s] = xp[s] * sqrtf(invd2[8 * l8 + s]);
            *(float4*)&H_s[n * STR + 8 * l8]     = make_float4(h[0],h[1],h[2],h[3]);
            *(float4*)&H_s[n * STR + 8 * l8 + 4] = make_float4(h[4],h[5],h[6],h[7]);
        }
    }
    __syncthreads();

    // ---- phase T: wave0 x-spill + Y-build + blocked backward | waves1,2 Gram
    //      | wave3 amean
    if (wv == 0) {
        // Spill x to x_s (U2s rows 32+; LmT2 dead after the barrier above).
        #pragma unroll
        for (int rr = 0; rr < 4; ++rr) {
            const int n = gr8 + 8 * rr;
            const float* xp = (rr == 0) ? xs0 : (rr == 1) ? xs1 : (rr == 2) ? xs2 : xs3;
            *(float4*)&x_s[n * STR + 8 * l8]     = make_float4(xp[0],xp[1],xp[2],xp[3]);
            *(float4*)&x_s[n * STR + 8 * l8 + 4] = make_float4(xp[4],xp[5],xp[6],xp[7]);
        }
        // Y-build: y[s] = sum_n x_n[8*l8+s] * phiw[n][aa] (== L^-1 K).
        const int aa = lw >> 3;
        float y[8] = {0.f,0.f,0.f,0.f,0.f,0.f,0.f,0.f};
        for (int n = 0; n < NN; ++n) {
            const float pw = phiwc[n * AA + aa];
            const float4 xa = *(const float4*)&x_s[n * STR + 8 * l8];
            const float4 xb = *(const float4*)&x_s[n * STR + 8 * l8 + 4];
            y[0] += xa.x * pw; y[1] += xa.y * pw;
            y[2] += xa.z * pw; y[3] += xa.w * pw;
            y[4] += xb.x * pw; y[5] += xb.y * pw;
            y[6] += xb.z * pw; y[7] += xb.w * pw;
        }
        #pragma unroll
        for (int s = 0; s < 8; ++s) y[s] *= invd1[8 * l8 + s];
        // Blocked backward solve (L^T z = y), 8x8 diagonal blocks.
        #pragma unroll 1
        for (int i8 = 7; i8 >= 0; --i8) {
            const int srcl = (lw & 56) | i8;
            float zs[8];
            #pragma unroll
            for (int s = 0; s < 8; ++s) zs[s] = __shfl(y[s], srcl, 64);
            // Lane-local redundant solve. SWZ(8*i8+ii, 8*i8) == 0: the
            // block-diagonal slice sits at group 0 -> broadcast reads.
            const float* rowb = &LmT1[(8 * i8) * STR];
            #pragma unroll
            for (int ii = 7; ii >= 0; --ii) {
                const float4 b0 = *(const float4*)&rowb[ii * STR + 0];
                const float4 b1 = *(const float4*)&rowb[ii * STR + 4];
                zs[ii] -= b0.x*zs[0] + b0.y*zs[1] + b0.z*zs[2] + b0.w*zs[3]
                        + b1.x*zs[4] + b1.y*zs[5] + b1.z*zs[6] + b1.w*zs[7];
            }
            if (l8 == i8) {
                #pragma unroll
                for (int s = 0; s < 8; ++s) y[s] = zs[s];
            } else if (l8 < i8) {
                const int ug = 8 * (i8 ^ l8);      // SWZ(8*l8+s, 8*i8)
                #pragma unroll
                for (int s = 0; s < 8; ++s) {
                    const float4 u0 = *(const float4*)&LmT1[(8*l8+s) * STR + ug];
                    const float4 u1 = *(const float4*)&LmT1[(8*l8+s) * STR + ug + 4];
                    y[s] -= u0.x*zs[0] + u0.y*zs[1] + u0.z*zs[2] + u0.w*zs[3]
                          + u1.x*zs[4] + u1.y*zs[5] + u1.z*zs[6] + u1.w*zs[7];
                }
            }
        }
        // cp_s overlays x_s base: x fully consumed by Y-build (same wave).
        #pragma unroll
        for (int s = 0; s < 8; ++s)
            cp_s[(8 * l8 + s) * W9 + aa] = y[s] * invl_s[8 * l8 + s];
    } else if (wv == 3) {
        if (lw < AA) {
            const int a = lw;
            float am = 0.f;
            for (int n = 0; n < NN; ++n) am += phiwc[n * AA + a];
            am_s[a] = am;
        }
    } else {
        // Gram pairs: 16 groups (waves 1,2) x 2 rows (n0=g, n1=g+16)
        const int g16 = (lw >> 3) + 8 * (wv - 1);
        const int n0 = g16, n1 = g16 + 16;
        float acc0[4] = {0.f,0.f,0.f,0.f}, acc1[4] = {0.f,0.f,0.f,0.f};
        const int rot = 2 * l8;
        #pragma unroll 2
        for (int e = 0; e < 16; ++e) {
            const int e4 = 4 * ((e + rot) & 15);
            const float4 hn0 = *(const float4*)&H_s[n0 * STR + e4];
            const float4 hn1 = *(const float4*)&H_s[n1 * STR + e4];
            #pragma unroll
            for (int mm = 0; mm < 4; ++mm) {
                const float4 hm = *(const float4*)&H_s[(4 * l8 + mm) * STR + e4];
                {
                    float s0 = hn0.x + hm.x, s1 = hn0.y + hm.y;
                    float s2 = hn0.z + hm.z, s3 = hn0.w + hm.w;
                    acc0[mm] += s0*s0 + s1*s1 + s2*s2 + s3*s3;
                }
                {
                    float s0 = hn1.x + hm.x, s1 = hn1.y + hm.y;
                    float s2 = hn1.z + hm.z, s3 = hn1.w + hm.w;
                    acc1[mm] += s0*s0 + s1*s1 + s2*s2 + s3*s3;
                }
            }
        }
        const float4 e1a = *(const float4*)&ws[n0 * NN + 4 * l8];
        const float4 e1b = *(const float4*)&ws[n1 * NN + 4 * l8];
        float Q0a = cq * expf(e1a.x - 0.5f * acc0[0]);
        float Q1a = cq * expf(e1a.y - 0.5f * acc0[1]);
        float Q2a = cq * expf(e1a.z - 0.5f * acc0[2]);
        float Q3a = cq * expf(e1a.w - 0.5f * acc0[3]);
        float Q0b = cq * expf(e1b.x - 0.5f * acc1[0]);
        float Q1b = cq * expf(e1b.y - 0.5f * acc1[1]);
        float Q2b = cq * expf(e1b.z - 0.5f * acc1[2]);
        float Q3b = cq * expf(e1b.w - 0.5f * acc1[3]);
        float ua[8], ub[8];
        #pragma unroll
        for (int a = 0; a < 8; ++a) {
            const float w0 = w9_s[(4*l8+0)*W9 + a], w1 = w9_s[(4*l8+1)*W9 + a];
            const float w2 = w9_s[(4*l8+2)*W9 + a], w3 = w9_s[(4*l8+3)*W9 + a];
            ua[a] = Q0a*w0 + Q1a*w1 + Q2a*w2 + Q3a*w3;
            ub[a] = Q0b*w0 + Q1b*w1 + Q2b*w2 + Q3b*w3;
            ua[a] += __shfl_xor(ua[a], 1, 64);
            ua[a] += __shfl_xor(ua[a], 2, 64);
            ua[a] += __shfl_xor(ua[a], 4, 64);
            ub[a] += __shfl_xor(ub[a], 1, 64);
            ub[a] += __shfl_xor(ub[a], 2, 64);
            ub[a] += __shfl_xor(ub[a], 4, 64);
        }
        float uva = (l8 == 0) ? ua[0] : (l8 == 1) ? ua[1] : (l8 == 2) ? ua[2] : (l8 == 3) ? ua[3]
                  : (l8 == 4) ? ua[4] : (l8 == 5) ? ua[5] : (l8 == 6) ? ua[6] : ua[7];
        float uvb = (l8 == 0) ? ub[0] : (l8 == 1) ? ub[1] : (l8 == 2) ? ub[2] : (l8 == 3) ? ub[3]
                  : (l8 == 4) ? ub[4] : (l8 == 5) ? ub[5] : (l8 == 6) ? ub[6] : ub[7];
        U_s[n0 * W9 + l8] = uva;
        U_s[n1 * W9 + l8] = uvb;
    }
    __syncthreads();

    // ---- phase C: acr = w^T U ----
    if (t < 64) {
        const int a = t >> 3, c = t & 7;
        float acc2 = 0.f;
        for (int n = 0; n < NN; ++n) acc2 += w9_s[n * W9 + a] * U_s[n * W9 + c];
        acr_s[a * W9 + c] = acc2;
    }
    __syncthreads();

    // ---- squash + outputs ----
    float* out0 = out;
    float* out1 = out + (size_t)NBATCH * AA;
    float* out2 = out + (size_t)NBATCH * AA + (size_t)NBATCH * AA * AA;
    if (t < 64) {
        const int a = t >> 3, c = t & 7;
        const float ama = am_s[a], amc = am_s[c];
        const float vac = 0.5f * (acr_s[a * W9 + c] + acr_s[c * W9 + a])
                        - ama * amc + ((a == c) ? 1e-6f : 0.0f);
        const float dca = acr_s[a * W9 + a] - ama * ama + 1e-6f;
        const float dcc = acr_s[c * W9 + c] - amc * amc + 1e-6f;
        const float q = expf(-0.5f * (dca + dcc));
        // expm1 formulation avoids catastrophic cancellation at vac ~ 1e-6
        const float sq = 0.5f * q * (expm1f(vac) * cosf(ama - amc)
                                   - expm1f(-vac) * cosf(ama + amc));
        out1[(size_t)b * 64 + t] = sq;
        if (t < AA) {
            float dct = acr_s[t * W9 + t] - am_s[t] * am_s[t] + 1e-6f;
            float e = expf(-0.5f * dct);
            out0[(size_t)b * AA + t] = e * sinf(am_s[t]);
            Ca_s[t] = e * cosf(am_s[t]);
        }
    }
    __syncthreads();
    #pragma unroll
    for (int e = 0; e < 2; ++e) {
        int idx = t + 256 * e;
        out2[(size_t)b * 512 + idx] = cp_s[(idx >> 3) * W9 + (idx & 7)] * Ca_s[idx & 7];
    }
}

extern "C" void kernel_launch(void* const* d_in, const int* in_sizes, int n_in,
                              void* d_out, int out_size, void* d_ws, size_t ws_size,
                              hipStream_t stream) {
    (void)in_sizes; (void)n_in; (void)out_size; (void)ws_size;
    const float* mean    = (const float*)d_in[0];
    const float* cov     = (const float*)d_in[1];
    const float* centers = (const float*)d_in[2];
    const float* weights = (const float*)d_in[3];
    const float* ls      = (const float*)d_in[4];
    float* ws = (float*)d_ws;
    float* o  = (float*)d_out;
    rbf_prep<<<4, 256, 0, stream>>>(centers, ls, ws);
    rbf_main<<<NBATCH, 256, 0, stream>>>(mean, cov, centers, weights, ls, ws, o);
}